// Round 8
// baseline (80.570 us; speedup 1.0000x reference)
//
#include <hip/hip_runtime.h>

#define N_REAL 12
#define BATCH  4
#define CH     3
#define HH     256
#define WW     256
#define KK     4
#define TY     8                  // output rows per block (full 256-wide rows)
#define NTHR   256
#define HW     (HH * WW)

typedef float f32x4 __attribute__((ext_vector_type(4)));

__device__ __forceinline__ float sigmoidf(float x) {
    float e = __builtin_amdgcn_exp2f(x * -1.44269504088896340736f);
    return __builtin_amdgcn_rcpf(1.0f + e);
}

__device__ __forceinline__ float lanepull(float x, int idx4) {
    return __int_as_float(__builtin_amdgcn_ds_bpermute(idx4, __float_as_int(x)));
}

__global__ __launch_bounds__(NTHR, 4)   // cap 128 VGPR; expect ~64-80
void reverb_fused(const float* __restrict__ states,
                  const float* __restrict__ weights,
                  const float* __restrict__ bias,
                  float*       __restrict__ out)
{
    const int ty  = blockIdx.x;            // 0..31
    const int b   = blockIdx.y;            // batch
    const int v   = blockIdx.z;            // dest node
    const int tid = threadIdx.x;
    const int w   = tid >> 6;              // wave 0..3: owns output rows 2w, 2w+1
    const int ln  = tid & 63;              // lane: owns cols 4ln..4ln+3
    const int gy0 = ty * TY;
    const int deg = (v == 0) ? 4 : 3;

    const int idxL = ((ln - 1) & 63) << 2; // bpermute byte indices, built once
    const int idxR = ((ln + 1) & 63) << 2;
    const bool lEdge = (ln == 0);
    const bool rEdge = (ln == 63);

    float acc[CH][2][4];
    #pragma unroll
    for (int co = 0; co < CH; ++co)
        #pragma unroll
        for (int yy = 0; yy < 2; ++yy)
            #pragma unroll
            for (int p = 0; p < 4; ++p) acc[co][yy][p] = 0.0f;
    float bsum[CH] = {0.f, 0.f, 0.f};

    // 5 input rows this thread needs: gy = gy0 + 2w + lr - 1, lr = 0..4
    const int gybase = gy0 + 2 * w - 1;
    int rowoff[5];
    bool rowok[5];
    #pragma unroll
    for (int lr = 0; lr < 5; ++lr) {
        const int gy  = gybase + lr;
        const int gyc = gy < 0 ? 0 : (gy > HH - 1 ? HH - 1 : gy);
        rowoff[lr] = gyc * WW + 4 * ln;
        rowok[lr]  = (unsigned)gy < (unsigned)HH;   // wave-uniform
    }

    for (int ei = 0; ei < deg; ++ei) {
        const int uc = (ei == 3) ? 12 : ((v + 11 - ei) % 12);
        const int e  = (ei == 3) ? 36 : (uc * 3 + ei);
        const float* __restrict__ srcE  = states + (size_t)(uc * BATCH + b) * CH * HW;
        const float* __restrict__ wbase = weights + e * (CH * CH * KK * KK);
        bsum[0] += bias[e * CH + 0];
        bsum[1] += bias[e * CH + 1];
        bsum[2] += bias[e * CH + 2];

        #pragma unroll
        for (int ci = 0; ci < CH; ++ci) {
            const float* __restrict__ srcC = srcE + (size_t)ci * HW;

            // ---- issue all 5 row loads (coalesced 1KB/wave each) ----
            f32x4 q[5];
            #pragma unroll
            for (int lr = 0; lr < 5; ++lr)
                q[lr] = *(const f32x4*)(srcC + rowoff[lr]);

            // ---- per row: sigmoid -> lane halo (convergent!) -> FMA ----
            #pragma unroll
            for (int lr = 0; lr < 5; ++lr) {
                f32x4 s;
                if (rowok[lr]) {
                    s.x = sigmoidf(q[lr].x); s.y = sigmoidf(q[lr].y);
                    s.z = sigmoidf(q[lr].z); s.w = sigmoidf(q[lr].w);
                } else {
                    s = (f32x4){0.f, 0.f, 0.f, 0.f};
                }
                // unconditional pulls (full EXEC), select AFTER:
                const float pL  = lanepull(s.w, idxL);
                const float pR0 = lanepull(s.x, idxR);
                const float pR1 = lanepull(s.y, idxR);
                const float vL  = lEdge ? 0.f : pL;
                const float vR0 = rEdge ? 0.f : pR0;
                const float vR1 = rEdge ? 0.f : pR1;
                const float vv[7] = {vL, s.x, s.y, s.z, s.w, vR0, vR1};

                #pragma unroll
                for (int yy = 0; yy < 2; ++yy) {
                    const int ky = lr - yy;
                    if (ky < 0 || ky > 3) continue;
                    #pragma unroll
                    for (int co = 0; co < CH; ++co) {
                        const f32x4 wv =
                            *(const f32x4*)(wbase + ((co * CH + ci) * KK + ky) * KK);
                        #pragma unroll
                        for (int p = 0; p < 4; ++p) {
                            acc[co][yy][p] = fmaf(wv.x, vv[p + 0], acc[co][yy][p]);
                            acc[co][yy][p] = fmaf(wv.y, vv[p + 1], acc[co][yy][p]);
                            acc[co][yy][p] = fmaf(wv.z, vv[p + 2], acc[co][yy][p]);
                            acc[co][yy][p] = fmaf(wv.w, vv[p + 3], acc[co][yy][p]);
                        }
                    }
                }
            }
        }
    }

    const float inv = 1.0f / (float)deg;
    const size_t obase = (size_t)(v * BATCH + b) * CH * HW;
    #pragma unroll
    for (int co = 0; co < CH; ++co) {
        #pragma unroll
        for (int yy = 0; yy < 2; ++yy) {
            const int oy = gy0 + 2 * w + yy;
            f32x4 o;
            o.x = (acc[co][yy][0] + bsum[co]) * inv;
            o.y = (acc[co][yy][1] + bsum[co]) * inv;
            o.z = (acc[co][yy][2] + bsum[co]) * inv;
            o.w = (acc[co][yy][3] + bsum[co]) * inv;
            __builtin_nontemporal_store(o,
                (f32x4*)&out[obase + (size_t)co * HW + (size_t)oy * WW + 4 * ln]);
        }
    }
}

extern "C" void kernel_launch(void* const* d_in, const int* in_sizes, int n_in,
                              void* d_out, int out_size, void* d_ws, size_t ws_size,
                              hipStream_t stream)
{
    const float* states  = (const float*)d_in[0];
    const float* weights = (const float*)d_in[1];
    const float* bias    = (const float*)d_in[2];
    float*       out     = (float*)d_out;

    dim3 grid(HH / TY, BATCH, N_REAL);     // 32 x 4 x 12 = 1536 blocks
    reverb_fused<<<grid, NTHR, 0, stream>>>(states, weights, bias, out);
}

// Round 9
// 53.151 us; speedup vs baseline: 1.5159x; 1.5159x over previous
//
#include <hip/hip_runtime.h>

#define N_REAL 12
#define BATCH  4
#define CH     3
#define HH     256
#define WW     256
#define KK     4
#define TY     8                  // output rows per tile (full 256-wide rows)
#define ROWSR  11                 // TY + KK - 1 input rows
#define RSTR   264                // LDS row stride (dwords): 256 data + 8 zero pad
#define NTHR   256
#define HW     (HH * WW)
#define NPAD   (4 + ROWSR * 8)    // guard quad + per-row pad dwords to zero once

typedef float f32x4 __attribute__((ext_vector_type(4)));

__device__ __forceinline__ float sigmoidf(float x) {
    float e = __builtin_amdgcn_exp2f(x * -1.44269504088896340736f);
    return __builtin_amdgcn_rcpf(1.0f + e);
}

__global__ __launch_bounds__(NTHR, 4)   // cap 128 VGPR -> allocator lands ~64, NO spill
void reverb_fused(const float* __restrict__ states,
                  const float* __restrict__ weights,
                  const float* __restrict__ bias,
                  float*       __restrict__ out)
{
    // guard(4) + 11 rows * 264; rows start 16B-aligned; pads stay zero forever.
    __shared__ __align__(16) float S[4 + ROWSR * RSTR];   // 11.6 KB

    const int ty  = blockIdx.x;            // 0..31
    const int b   = blockIdx.y;            // batch
    const int v   = blockIdx.z;            // dest node
    const int tid = threadIdx.x;
    const int w   = tid >> 6;              // wave 0..3 == output row-pair owner
    const int ln  = tid & 63;              // lane == output col-quad
    const int gy0 = ty * TY;
    const int deg = (v == 0) ? 4 : 3;

    // ---- one-time zeroing of guard + row pads (never overwritten) ----
    if (tid < NPAD) {
        if (tid < 4) S[tid] = 0.0f;
        else {
            const int i = tid - 4;
            S[4 + (i >> 3) * RSTR + 256 + (i & 7)] = 0.0f;
        }
    }

    float acc[CH][2][4];
    #pragma unroll
    for (int co = 0; co < CH; ++co)
        #pragma unroll
        for (int yy = 0; yy < 2; ++yy)
            #pragma unroll
            for (int p = 0; p < 4; ++p) acc[co][yy][p] = 0.0f;
    float bsum[CH] = {0.f, 0.f, 0.f};

    for (int ei = 0; ei < deg; ++ei) {
        const int uc = (ei == 3) ? 12 : ((v + 11 - ei) % 12);
        const int e  = (ei == 3) ? 36 : (uc * 3 + ei);
        const float* __restrict__ srcE = states + (size_t)(uc * BATCH + b) * CH * HW;
        const float* __restrict__ wbase = weights + e * (CH * CH * KK * KK);
        bsum[0] += bias[e * CH + 0];
        bsum[1] += bias[e * CH + 1];
        bsum[2] += bias[e * CH + 2];

        #pragma unroll
        for (int ci = 0; ci < CH; ++ci) {
            const float* __restrict__ srcC = srcE + (size_t)ci * HW;

            __syncthreads();               // previous phase's readers done

            // ---- stage: wave w owns rows w, w+4, w+8 (clamped loads, OOB->0) ----
            #pragma unroll
            for (int k = 0; k < 3; ++k) {
                const int r = w + 4 * k;
                if (r < ROWSR) {           // wave-uniform (only w=3,k=2 skips)
                    const int gy  = gy0 + r - 1;          // SAME pad lo=1
                    const int gyc = gy < 0 ? 0 : (gy > HH - 1 ? HH - 1 : gy);
                    const f32x4 q = *(const f32x4*)(srcC + gyc * WW + 4 * ln);
                    f32x4 t;
                    if ((unsigned)gy < HH) {
                        t.x = sigmoidf(q.x); t.y = sigmoidf(q.y);
                        t.z = sigmoidf(q.z); t.w = sigmoidf(q.w);
                    } else {
                        t = (f32x4){0.f, 0.f, 0.f, 0.f};
                    }
                    *(f32x4*)(S + 4 + r * RSTR + 4 * ln) = t;
                }
            }
            __syncthreads();               // channel tile ready

            // ---- compute: 5 LDS rows -> 2 output rows, 3 co ----
            #pragma unroll
            for (int lr = 0; lr < 5; ++lr) {
                const float* rp = S + 4 + (2 * w + lr) * RSTR + 4 * ln;
                const f32x4 A  = *(const f32x4*)(rp - 4);   // A.w = x-1 (guard/pad)
                const f32x4 Bq = *(const f32x4*)(rp);
                const f32x4 Cq = *(const f32x4*)(rp + 4);   // x+4, x+5 (pad at edge)
                const float vv[7] = {A.w, Bq.x, Bq.y, Bq.z, Bq.w, Cq.x, Cq.y};
                #pragma unroll
                for (int yy = 0; yy < 2; ++yy) {
                    const int ky = lr - yy;
                    if (ky < 0 || ky > 3) continue;
                    #pragma unroll
                    for (int co = 0; co < CH; ++co) {
                        const f32x4 wv =
                            *(const f32x4*)(wbase + ((co * CH + ci) * KK + ky) * KK);
                        #pragma unroll
                        for (int p = 0; p < 4; ++p) {
                            acc[co][yy][p] = fmaf(wv.x, vv[p + 0], acc[co][yy][p]);
                            acc[co][yy][p] = fmaf(wv.y, vv[p + 1], acc[co][yy][p]);
                            acc[co][yy][p] = fmaf(wv.z, vv[p + 2], acc[co][yy][p]);
                            acc[co][yy][p] = fmaf(wv.w, vv[p + 3], acc[co][yy][p]);
                        }
                    }
                }
            }
        }
    }

    const float inv = 1.0f / (float)deg;
    const size_t obase = (size_t)(v * BATCH + b) * CH * HW;
    #pragma unroll
    for (int co = 0; co < CH; ++co) {
        #pragma unroll
        for (int yy = 0; yy < 2; ++yy) {
            const int oy = gy0 + 2 * w + yy;
            f32x4 o;
            o.x = (acc[co][yy][0] + bsum[co]) * inv;
            o.y = (acc[co][yy][1] + bsum[co]) * inv;
            o.z = (acc[co][yy][2] + bsum[co]) * inv;
            o.w = (acc[co][yy][3] + bsum[co]) * inv;
            __builtin_nontemporal_store(o,
                (f32x4*)&out[obase + (size_t)co * HW + (size_t)oy * WW + 4 * ln]);
        }
    }
}

extern "C" void kernel_launch(void* const* d_in, const int* in_sizes, int n_in,
                              void* d_out, int out_size, void* d_ws, size_t ws_size,
                              hipStream_t stream)
{
    const float* states  = (const float*)d_in[0];
    const float* weights = (const float*)d_in[1];
    const float* bias    = (const float*)d_in[2];
    float*       out     = (float*)d_out;

    dim3 grid(HH / TY, BATCH, N_REAL);     // 32 x 4 x 12 = 1536 blocks
    reverb_fused<<<grid, NTHR, 0, stream>>>(states, weights, bias, out);
}

// Round 10
// 50.314 us; speedup vs baseline: 1.6013x; 1.0564x over previous
//
#include <hip/hip_runtime.h>

#define N_REAL 12
#define BATCH  4
#define CH     3
#define HH     256
#define WW     256
#define KK     4
#define TY     8                  // output rows per tile (full 256-wide rows)
#define ROWSR  11                 // TY + KK - 1 input rows
#define RSTR   264                // LDS row stride (dwords): 256 data + 8 zero pad
#define NTHR   256
#define HW     (HH * WW)
#define BUFSZ  (4 + ROWSR * RSTR) // guard quad + rows
#define NPAD   (4 + ROWSR * 8)    // pad dwords to zero once per buffer (92)

typedef float f32x4 __attribute__((ext_vector_type(4)));

__device__ __forceinline__ float sigmoidf(float x) {
    float e = __builtin_amdgcn_exp2f(x * -1.44269504088896340736f);
    return __builtin_amdgcn_rcpf(1.0f + e);
}

__global__ __launch_bounds__(NTHR, 4)   // loose cap (128): allocator must NOT spill
void reverb_fused(const float* __restrict__ states,
                  const float* __restrict__ weights,
                  const float* __restrict__ bias,
                  float*       __restrict__ out)
{
    __shared__ __align__(16) float S[2][BUFSZ];   // 23.3 KB -> 6 blocks/CU

    const int ty  = blockIdx.x;            // 0..31
    const int b   = blockIdx.y;            // batch
    const int v   = blockIdx.z;            // dest node
    const int tid = threadIdx.x;
    const int w   = tid >> 6;              // wave 0..3 == output row-pair owner
    const int ln  = tid & 63;              // lane == output col-quad
    const int gy0 = ty * TY;
    const int deg = (v == 0) ? 4 : 3;
    const int P   = 3 * deg;               // total (edge,channel) phases

    // ---- one-time zeroing of guard + row pads in BOTH buffers ----
    if (tid < 2 * NPAD) {
        const int bi = (tid >= NPAD) ? 1 : 0;
        const int j  = tid - bi * NPAD;
        if (j < 4) S[bi][j] = 0.0f;
        else {
            const int i = j - 4;
            S[bi][4 + (i >> 3) * RSTR + 256 + (i & 7)] = 0.0f;
        }
    }

    // ---- staging metadata: wave w owns rows w, w+4, w+8 (r<11) ----
    int  goffs[3], soff[3];
    bool sok[3], rvalid[3];
    #pragma unroll
    for (int k = 0; k < 3; ++k) {
        const int r  = w + 4 * k;
        rvalid[k] = (r < ROWSR);           // wave-uniform; false only for w=3,k=2
        const int gy  = gy0 + r - 1;       // SAME pad lo=1
        const int gyc = gy < 0 ? 0 : (gy > HH - 1 ? HH - 1 : gy);
        goffs[k] = gyc * WW + 4 * ln;
        sok[k]   = (unsigned)gy < (unsigned)HH;
        soff[k]  = 4 + r * RSTR + 4 * ln;
    }

    // ---- edge tables (uniform) ----
    int ucA[4], eA[4];
    #pragma unroll
    for (int ei = 0; ei < 4; ++ei) {
        int t = v + 11 - ei; if (t >= 12) t -= 12;
        ucA[ei] = (ei == 3) ? 12 : t;
        eA[ei]  = (ei == 3) ? 36 : (ucA[ei] * 3 + ei);
    }

    // ---- bias sum once ----
    float bsum[CH] = {0.f, 0.f, 0.f};
    for (int ei = 0; ei < deg; ++ei) {
        bsum[0] += bias[eA[ei] * CH + 0];
        bsum[1] += bias[eA[ei] * CH + 1];
        bsum[2] += bias[eA[ei] * CH + 2];
    }

    float acc[CH][2][4];
    #pragma unroll
    for (int co = 0; co < CH; ++co)
        #pragma unroll
        for (int yy = 0; yy < 2; ++yy)
            #pragma unroll
            for (int p = 0; p < 4; ++p) acc[co][yy][p] = 0.0f;

    // ---- prologue: stage phase 0 into S[0] ----
    {
        const float* s0 = states + (size_t)(ucA[0] * BATCH + b) * CH * HW; // ci=0
        #pragma unroll
        for (int k = 0; k < 3; ++k) {
            if (rvalid[k]) {
                const f32x4 q = *(const f32x4*)(s0 + goffs[k]);
                f32x4 t;
                if (sok[k]) {
                    t.x = sigmoidf(q.x); t.y = sigmoidf(q.y);
                    t.z = sigmoidf(q.z); t.w = sigmoidf(q.w);
                } else t = (f32x4){0.f, 0.f, 0.f, 0.f};
                *(f32x4*)(&S[0][soff[k]]) = t;
            }
        }
    }
    __syncthreads();

    for (int p = 0; p < P; ++p) {
        const int bi = p & 1;
        const int ei = p / 3;
        const int ci = p - 3 * ei;

        // ---- issue next phase's loads (latency hidden under compute) ----
        f32x4 q[3];
        const bool more = (p + 1 < P);
        if (more) {
            const int p1  = p + 1;
            const int ei1 = p1 / 3;
            const int ci1 = p1 - 3 * ei1;
            const float* sn = states +
                (size_t)(ucA[ei1] * BATCH + b) * CH * HW + (size_t)ci1 * HW;
            #pragma unroll
            for (int k = 0; k < 3; ++k)
                if (rvalid[k]) q[k] = *(const f32x4*)(sn + goffs[k]);
        }

        // ---- compute phase p from S[bi] ----
        const float* __restrict__ wbase = weights + eA[ei] * (CH * CH * KK * KK);
        #pragma unroll
        for (int lr = 0; lr < 5; ++lr) {
            const float* rp = &S[bi][4 + (2 * w + lr) * RSTR + 4 * ln];
            const f32x4 A  = *(const f32x4*)(rp - 4);   // A.w = x-1 (guard/pad)
            const f32x4 Bq = *(const f32x4*)(rp);
            const f32x4 Cq = *(const f32x4*)(rp + 4);   // x+4, x+5 (pad at edge)
            const float vv[7] = {A.w, Bq.x, Bq.y, Bq.z, Bq.w, Cq.x, Cq.y};
            #pragma unroll
            for (int yy = 0; yy < 2; ++yy) {
                const int ky = lr - yy;
                if (ky < 0 || ky > 3) continue;
                #pragma unroll
                for (int co = 0; co < CH; ++co) {
                    const f32x4 wv =
                        *(const f32x4*)(wbase + ((co * CH + ci) * KK + ky) * KK);
                    #pragma unroll
                    for (int pp = 0; pp < 4; ++pp) {
                        acc[co][yy][pp] = fmaf(wv.x, vv[pp + 0], acc[co][yy][pp]);
                        acc[co][yy][pp] = fmaf(wv.y, vv[pp + 1], acc[co][yy][pp]);
                        acc[co][yy][pp] = fmaf(wv.z, vv[pp + 2], acc[co][yy][pp]);
                        acc[co][yy][pp] = fmaf(wv.w, vv[pp + 3], acc[co][yy][pp]);
                    }
                }
            }
        }

        // ---- sigmoid + write next phase into S[bi^1] ----
        if (more) {
            #pragma unroll
            for (int k = 0; k < 3; ++k) {
                if (rvalid[k]) {
                    f32x4 t;
                    if (sok[k]) {
                        t.x = sigmoidf(q[k].x); t.y = sigmoidf(q[k].y);
                        t.z = sigmoidf(q[k].z); t.w = sigmoidf(q[k].w);
                    } else t = (f32x4){0.f, 0.f, 0.f, 0.f};
                    *(f32x4*)(&S[bi ^ 1][soff[k]]) = t;
                }
            }
        }
        __syncthreads();                    // single barrier per phase
    }

    const float inv = 1.0f / (float)deg;
    const size_t obase = (size_t)(v * BATCH + b) * CH * HW;
    #pragma unroll
    for (int co = 0; co < CH; ++co) {
        #pragma unroll
        for (int yy = 0; yy < 2; ++yy) {
            const int oy = gy0 + 2 * w + yy;
            f32x4 o;
            o.x = (acc[co][yy][0] + bsum[co]) * inv;
            o.y = (acc[co][yy][1] + bsum[co]) * inv;
            o.z = (acc[co][yy][2] + bsum[co]) * inv;
            o.w = (acc[co][yy][3] + bsum[co]) * inv;
            __builtin_nontemporal_store(o,
                (f32x4*)&out[obase + (size_t)co * HW + (size_t)oy * WW + 4 * ln]);
        }
    }
}

extern "C" void kernel_launch(void* const* d_in, const int* in_sizes, int n_in,
                              void* d_out, int out_size, void* d_ws, size_t ws_size,
                              hipStream_t stream)
{
    const float* states  = (const float*)d_in[0];
    const float* weights = (const float*)d_in[1];
    const float* bias    = (const float*)d_in[2];
    float*       out     = (float*)d_out;

    dim3 grid(HH / TY, BATCH, N_REAL);     // 32 x 4 x 12 = 1536 blocks, 6/CU resident
    reverb_fused<<<grid, NTHR, 0, stream>>>(states, weights, bias, out);
}